// Round 3
// baseline (1471.400 us; speedup 1.0000x reference)
//
#include <hip/hip_runtime.h>
#include <hip/hip_bf16.h>

// MyRnn: h_t = tanh(emb[idx_t] @ W_xh + b_h + h_{t-1} @ W_hh), 80 steps,
// out = sigmoid(h_80 @ W_out + b_out).
//
// R5: NAMED-REGISTER stream pipeline. R2-R4 post-mortem: every round had
// VGPR_Count pinned at exactly 128 with 36-49MB WRITE_SIZE regardless of
// launch_bounds / waves_per_eu / asm pins / live-set size -> the fragment
// ARRAYS (whh[][], sB[][] passed by pointer into a lambda) were placed in
// scratch memory (SROA failure), not regalloc-spilled. Every MFMA B-operand
// was a scratch read: ~84MB/step scratch traffic, 24MB/step L2 miss,
// MfmaUtil 3-4%, 13-17us/step of serialized scratch latency.
//
// Fix: ZERO fragment arrays. 4-deep L2-stream pipeline in 16 individually
// named bf16x8 regs (pA0..pD3), accumulators in 4 named f32x4, all kstep
// indices compile-time macro constants. ~110 VGPR live -> nothing can go
// to scratch. 20 unified ksteps (0..3 = W_xh on x_t, 4..19 = W_hh on h);
// weight loads are t-invariant so the pipeline crosses the step barrier
// (last quad prefetches ksteps 0..3 for the next step).
// Weights pre-swizzled to MFMA-fragment order [wave][ks][nt][lane][16B]:
// each load = one contiguous 1KB wave transaction, L2-resident (640KB/XCD).

#define T_LEN   80
#define EMB_D   100
#define UNITS   512
#define ROWS    16
#define NBLK    128
#define NTHR    512
#define NT      4                // n-tiles (16 cols) per wave
#define KSH     16               // K-steps for W_hh (512/32)
#define KSX     4                // K-steps for W_xh (128/32, zero-padded)
#define KTOT    (KSH + KSX)      // 20 unified ksteps

typedef __bf16 bf16x8 __attribute__((ext_vector_type(8)));
typedef float  f32x4  __attribute__((ext_vector_type(4)));

__device__ __forceinline__ float fast_tanh(float x) {
    float e = __builtin_amdgcn_exp2f(x * 2.8853900817779268f);
    return 1.0f - 2.0f * __builtin_amdgcn_rcpf(1.0f + e);
}

// ---- prep: rewrite weights into MFMA-fragment order in d_ws ----
// FW[w][ks][nt][lane][8]: elem j = Whh[ks*32 + (lane>>4)*8 + j][w*64 + nt*16 + (lane&15)]
// FX[w][ks][nt][lane][8]: same from Wxh, k >= 100 -> 0
__global__ void prep_kernel(const float* __restrict__ Whh,
                            const float* __restrict__ Wxh,
                            __bf16* __restrict__ FW, __bf16* __restrict__ FX) {
    const int f = blockIdx.x * 256 + threadIdx.x;
    if (f < 32768) {
        const int lane = f & 63, nt = (f >> 6) & 3, ks = (f >> 8) & 15, w = f >> 12;
        const int c  = (w << 6) + (nt << 4) + (lane & 15);
        const int kb = (ks << 5) + ((lane >> 4) << 3);
        __bf16* d = FW + (size_t)f * 8;
        #pragma unroll
        for (int j = 0; j < 8; ++j)
            d[j] = (__bf16)Whh[(kb + j) * UNITS + c];
    } else {
        const int f2 = f - 32768;
        const int lane = f2 & 63, nt = (f2 >> 6) & 3, ks = (f2 >> 8) & 3, w = f2 >> 10;
        const int c  = (w << 6) + (nt << 4) + (lane & 15);
        const int kb = (ks << 5) + ((lane >> 4) << 3);
        __bf16* d = FX + (size_t)f2 * 8;
        #pragma unroll
        for (int j = 0; j < 8; ++j)
            d[j] = (kb + j < EMB_D) ? (__bf16)Wxh[(kb + j) * UNITS + c] : (__bf16)0.0f;
    }
}

// prefetch kstep KK's 4 B-frags into named slot P (KK is a literal)
#define PF(KK, P) do {                                                        \
    const __bf16* _p = ((KK) < KSX) ? (fxp + ((KK) << 11))                    \
                                    : (fwp + (((KK) - KSX) << 11));           \
    P##0 = *(const bf16x8*)(_p);                                              \
    P##1 = *(const bf16x8*)(_p + 512);                                        \
    P##2 = *(const bf16x8*)(_p + 1024);                                       \
    P##3 = *(const bf16x8*)(_p + 1536);                                       \
} while (0)

// consume kstep KK from named slot P (A-frag from LDS, 4 MFMAs)
#define MM(KK, P) do {                                                        \
    bf16x8 _a;                                                                \
    if ((KK) < KSX) _a = *(const bf16x8*)&xb_r[xbase + (((KK) ^ kx) << 5)];   \
    else            _a = *(const bf16x8*)&hb_r[hbase + ((((KK) - KSX) ^ kx) << 5)]; \
    acc0 = __builtin_amdgcn_mfma_f32_16x16x32_bf16(_a, P##0, acc0, 0, 0, 0);  \
    acc1 = __builtin_amdgcn_mfma_f32_16x16x32_bf16(_a, P##1, acc1, 0, 0, 0);  \
    acc2 = __builtin_amdgcn_mfma_f32_16x16x32_bf16(_a, P##2, acc2, 0, 0, 0);  \
    acc3 = __builtin_amdgcn_mfma_f32_16x16x32_bf16(_a, P##3, acc3, 0, 0, 0);  \
} while (0)

#define KQUAD(K0, K1, K2, K3, N0, N1, N2, N3)                                 \
    MM(K0, pA); PF(N0, pA);                                                   \
    MM(K1, pB); PF(N1, pB);                                                   \
    MM(K2, pC); PF(N2, pC);                                                   \
    MM(K3, pD); PF(N3, pD);

// write h' tile NT_ from ACC: C/D layout col=ln, row=4q+i, XOR-swizzled LDS
#define HWR(NT_, ACC) {                                                       \
    const int cc = (wave << 3) + ((NT_) << 1) + (ln >> 3);                    \
    _Pragma("unroll")                                                         \
    for (int i = 0; i < 4; ++i) {                                             \
        const int row = (q << 2) + i;                                         \
        hb_w[(row << 9) + (((cc ^ (row & 7)) << 3) | e7)] =                   \
            (__bf16)fast_tanh(ACC[i]);                                        \
    }                                                                         \
}

#define STEP(HB_R, XB_R, HB_W) do {                                           \
    const __bf16* const hb_r = (HB_R);                                        \
    const __bf16* const xb_r = (XB_R);                                        \
    __bf16* const hb_w = (HB_W);                                              \
    f32x4 acc0 = {bhv0, bhv0, bhv0, bhv0};                                    \
    f32x4 acc1 = {bhv1, bhv1, bhv1, bhv1};                                    \
    f32x4 acc2 = {bhv2, bhv2, bhv2, bhv2};                                    \
    f32x4 acc3 = {bhv3, bhv3, bhv3, bhv3};                                    \
    KQUAD(0, 1, 2, 3,     4, 5, 6, 7)                                         \
    KQUAD(4, 5, 6, 7,     8, 9, 10, 11)                                       \
    KQUAD(8, 9, 10, 11,   12, 13, 14, 15)                                     \
    KQUAD(12, 13, 14, 15, 16, 17, 18, 19)                                     \
    KQUAD(16, 17, 18, 19, 0, 1, 2, 3)                                         \
    HWR(0, acc0) HWR(1, acc1) HWR(2, acc2) HWR(3, acc3)                       \
} while (0)

__global__ __launch_bounds__(NTHR, 1)
void rnn_kernel(const int*   __restrict__ inputs,   // [2048][80]
                const float* __restrict__ emb,      // [35000][100]
                const float* __restrict__ bh,       // [512]
                const float* __restrict__ Wout,     // [512]
                const float* __restrict__ bout,     // [1]
                const __bf16* __restrict__ FW,      // frag-order Whh (ws)
                const __bf16* __restrict__ FX,      // frag-order Wxh (ws)
                float*       __restrict__ out)      // [2048]
{
    // h: 16 rows x 512 bf16, 16B-chunk XOR swizzle:
    //   elem(m,k) = m*512 + (((k>>3) ^ (m&7))<<3) + (k&7)
    // x: 16 rows x 128 bf16, same swizzle, row stride 128.
    __shared__ alignas(16) __bf16 hbuf[2][16 * UNITS];
    __shared__ alignas(16) __bf16 xbuf[2][16 * 128];

    const int tid  = threadIdx.x;
    const int wave = tid >> 6;       // 0..7
    const int lane = tid & 63;
    const int q    = lane >> 4;      // MFMA quad
    const int ln   = lane & 15;
    const int e7   = ln & 7;
    const int qa   = q ^ (e7 & 3);
    const int kx   = e7 >> 2;
    const int r0   = blockIdx.x * ROWS;

    const float bhv0 = bh[(wave << 6) + 0  + ln];
    const float bhv1 = bh[(wave << 6) + 16 + ln];
    const float bhv2 = bh[(wave << 6) + 32 + ln];
    const float bhv3 = bh[(wave << 6) + 48 + ln];

    const __bf16* const fxp = FX + (wave << 13) + (lane << 3);
    const __bf16* const fwp = FW + (wave << 15) + (lane << 3);
    const int xbase = (ln << 7) + (qa << 3);
    const int hbase = (ln << 9) + (qa << 3);

    // 4-deep stream pipeline: 16 named bf16x8 slots (64 VGPR)
    bf16x8 pA0, pA1, pA2, pA3;
    bf16x8 pB0, pB1, pB2, pB3;
    bf16x8 pC0, pC1, pC2, pC3;
    bf16x8 pD0, pD1, pD2, pD3;

    // zero LDS (h0 = 0; x pad cols k>=100 stay 0 forever)
    {
        int4 z; z.x = z.y = z.z = z.w = 0;
        int4* hp = (int4*)&hbuf[0][0];
        #pragma unroll
        for (int i = 0; i < 4; ++i) hp[tid + i * NTHR] = z;   // 32KB
        int4* xp = (int4*)&xbuf[0][0];
        xp[tid] = z;                                          // 8KB
    }

    // stage embedded x_t (bf16, swizzled); wave w does rows w and w+8
    auto stage = [&](int t, __bf16* xb) {
        #pragma unroll
        for (int rr = 0; rr < 2; ++rr) {
            const int r = wave + (rr << 3);
            const int idxv = inputs[(r0 + r) * T_LEN + t];
            const float* er = emb + (size_t)idxv * EMB_D;
            const int k0 = lane;          // < 100 always
            xb[(r << 7) + ((((k0 >> 3) ^ (r & 7)) << 3) | (k0 & 7))] = (__bf16)er[k0];
            const int k1 = lane + 64;
            if (k1 < EMB_D)
                xb[(r << 7) + ((((k1 >> 3) ^ (r & 7)) << 3) | (k1 & 7))] = (__bf16)er[k1];
        }
    };

    // pipeline prologue: slots <- ksteps 0..3 (the X-frags)
    PF(0, pA); PF(1, pB); PF(2, pC); PF(3, pD);

    stage(0, xbuf[0]);
    __syncthreads();

    #pragma unroll 1
    for (int t = 0; t < T_LEN; t += 2) {
        stage(t + 1, xbuf[1]);                        // t+1 <= 79
        STEP(hbuf[0], xbuf[0], hbuf[1]);
        __syncthreads();
        if (t + 2 < T_LEN) stage(t + 2, xbuf[0]);
        STEP(hbuf[1], xbuf[1], hbuf[0]);
        __syncthreads();
    }
    // h_last in hbuf[0], rows 0..15

    // output head: wave w reduces rows w and w+8
    #pragma unroll
    for (int rr = 0; rr < 2; ++rr) {
        const int m = wave + (rr << 3);
        const bf16x8 hv = *(const bf16x8*)&hbuf[0][(m << 9) + ((lane ^ wave) << 3)];
        float s = 0.0f;
        #pragma unroll
        for (int j = 0; j < 8; ++j)
            s += (float)hv[j] * Wout[(lane << 3) + j];
        #pragma unroll
        for (int off = 32; off > 0; off >>= 1)
            s += __shfl_down(s, off, 64);
        if (lane == 0) {
            const float logit = s + bout[0];
            out[r0 + m] = __builtin_amdgcn_rcpf(
                1.0f + __builtin_amdgcn_exp2f(-logit * 1.4426950408889634f));
        }
    }
}

extern "C" void kernel_launch(void* const* d_in, const int* in_sizes, int n_in,
                              void* d_out, int out_size, void* d_ws, size_t ws_size,
                              hipStream_t stream) {
    __bf16* FW = (__bf16*)d_ws;                 // 512*512*2 = 512 KB (frag order)
    __bf16* FX = FW + UNITS * UNITS;            // 512*128*2 = 128 KB (frag order)
    prep_kernel<<<dim3(160), dim3(256), 0, stream>>>(
        (const float*)d_in[3],   // W_hh
        (const float*)d_in[2],   // W_xh
        FW, FX);
    rnn_kernel<<<dim3(NBLK), dim3(NTHR), 0, stream>>>(
        (const int*)d_in[0],     // inputs
        (const float*)d_in[1],   // emb_table
        (const float*)d_in[4],   // b_h
        (const float*)d_in[5],   // W_out
        (const float*)d_in[6],   // b_out
        FW, FX,
        (float*)d_out);
}